// Round 17
// baseline (35.013 us; speedup 1.0000x reference)
//
#include <hip/hip_runtime.h>
#include <hip/hip_bf16.h>

// Problem constants: B=1, N=1024, T=2048, E=16384, K=32.
#define TT  2048
#define KK  32
#define NN  1024
#define EE  16384
#define CAP 64     // per-row expert cap (Poisson(16); P(>64) ~ 1e-21)
#define RS  2080   // padded i8 row stride: [32 causal zeros | 2048 row]

typedef int   int4v __attribute__((ext_vector_type(4)));
typedef float f32x4 __attribute__((ext_vector_type(4)));

// Device-global prepped data (rewritten every call).
__device__ __align__(16) char  g_xi8[NN * RS];   // 2.13 MB quantized x rows
__device__ __align__(16) char  g_ki8[EE * KK];   // 0.5 MB quantized taps
__device__ float g_xs[NN];                       // per-row x scales

// Async global->LDS DMA, 16 B per ACTIVE lane (dest = uniform base + lane*16).
__device__ __forceinline__ void gload_lds16(const char* g, char* l) {
    __builtin_amdgcn_global_load_lds(
        (const __attribute__((address_space(1))) void*)(const void*)(g),
        (__attribute__((address_space(3))) void*)(void*)(l), 16, 0, 0);
}

// Prep A: blocks 0..1023: x row -> per-row-scaled i8 (+32B zero halo) + scale;
// block 1024: zero cnt.
__global__ __launch_bounds__(256) void cvt_kernel(const float* __restrict__ x,
                                                  int* __restrict__ cnt) {
    const int bid = blockIdx.x, tid = threadIdx.x;
    if (bid == NN) { ((int4*)cnt)[tid] = make_int4(0, 0, 0, 0); return; }
    __shared__ float wmax[4];
    __shared__ float sinv[2];
    const float4* xr = (const float4*)(x + (size_t)bid * TT);
    const float4 u = xr[2 * tid], v = xr[2 * tid + 1];
    float m = fmaxf(fmaxf(fmaxf(fabsf(u.x), fabsf(u.y)), fmaxf(fabsf(u.z), fabsf(u.w))),
                    fmaxf(fmaxf(fabsf(v.x), fabsf(v.y)), fmaxf(fabsf(v.z), fabsf(v.w))));
    #pragma unroll
    for (int o = 32; o; o >>= 1) m = fmaxf(m, __shfl_xor(m, o));
    if ((tid & 63) == 0) wmax[tid >> 6] = m;
    __syncthreads();
    if (tid == 0) {
        float mx = fmaxf(fmaxf(wmax[0], wmax[1]), fmaxf(wmax[2], wmax[3]));
        mx = fmaxf(mx, 1e-20f);
        sinv[0] = mx / 127.0f;          // scale
        sinv[1] = 127.0f / mx;          // inverse
        g_xs[bid] = mx / 127.0f;
    }
    __syncthreads();
    const float inv = sinv[1];
    long pk = 0;
    #pragma unroll
    for (int j = 0; j < 8; ++j) {
        const float val = (j < 4) ? ((j == 0) ? u.x : (j == 1) ? u.y : (j == 2) ? u.z : u.w)
                                  : ((j == 4) ? v.x : (j == 5) ? v.y : (j == 6) ? v.z : v.w);
        int q = (int)rintf(val * inv);
        q = (q > 127) ? 127 : (q < -127 ? -127 : q);
        pk |= ((long)(unsigned char)(signed char)q) << (8 * j);
    }
    *(long*)&g_xi8[(size_t)bid * RS + 32 + 8 * tid] = pk;
    if (tid < 4) *(long*)&g_xi8[(size_t)bid * RS + 8 * tid] = 0L;   // causal halo
}

// Prep B: per-expert tap quantization + routing CSR with combined scale.
// slots[d*CAP+p] packs (src<<14)|e; sscale[d*CAP+p] = g_xs[src]*sk[e].
__global__ __launch_bounds__(256) void csr_kernel(const float* __restrict__ kern,
                                                  const int* __restrict__ src,
                                                  const int* __restrict__ dst,
                                                  int* __restrict__ cnt,
                                                  unsigned* __restrict__ slots,
                                                  float* __restrict__ sscale) {
    const int e = blockIdx.x * 256 + threadIdx.x;   // 16384 threads
    float kv[KK];
    float mk = 0.f;
    #pragma unroll
    for (int u = 0; u < 8; ++u) {
        const float4 t = *(const float4*)(kern + (size_t)e * KK + 4 * u);
        kv[4*u+0] = t.x; kv[4*u+1] = t.y; kv[4*u+2] = t.z; kv[4*u+3] = t.w;
        mk = fmaxf(mk, fmaxf(fmaxf(fabsf(t.x), fabsf(t.y)), fmaxf(fabsf(t.z), fabsf(t.w))));
    }
    mk = fmaxf(mk, 1e-20f);
    const float sk  = mk / 127.0f;
    const float inv = 127.0f / mk;
    int pw[8];
    #pragma unroll
    for (int u = 0; u < 8; ++u) {
        int w = 0;
        #pragma unroll
        for (int j = 0; j < 4; ++j) {
            int q = (int)rintf(kv[4*u+j] * inv);
            q = (q > 127) ? 127 : (q < -127 ? -127 : q);
            w |= ((int)(unsigned char)(signed char)q) << (8 * j);
        }
        pw[u] = w;
    }
    int4* kb = (int4*)(g_ki8 + (size_t)e * KK);
    kb[0] = make_int4(pw[0], pw[1], pw[2], pw[3]);
    kb[1] = make_int4(pw[4], pw[5], pw[6], pw[7]);
    const int d = dst[e], s = src[e];
    const int p = atomicAdd(&cnt[d], 1);
    if (p < CAP) {
        slots[(size_t)d * CAP + p]  = ((unsigned)s << 14) | (unsigned)e;
        sscale[(size_t)d * CAP + p] = g_xs[s] * sk;
    }
}

// Main: grid 1024 (row n), 128 thr = 2 parity waves (R16 structure, i8 data).
// Visit = expert over FULL row. Cluster = EXACTLY 4 VMEM {2x row DMA, tail DMA
// (2 lanes), tap dword}; 3-deep rotation, counted vmcnt(8/4/0).
// Verified MFMA slot math (R2-R16; slot-permutation cancels between A and B):
//   A1 b64 at xsb[256s + 16c + 8g] (i8 elems == bytes), A2 at +16, s in [0,8)
//   b1 = kt[a][s1..+8), b2 = kt[a][s1+16..+24) with g<2 -> 0 (REQUIRED)
//   kt[a][((a+1)&7)+47-m] = tap[m];  a=c&7, s1=((a+1)&7)+15-c+8g (8-aligned)
//   Per visit: i32 MFMA pair with C=0, then acc_f += (sx*sk) * i32 result.
//   D: col=c=lane&15, row=4g+qd -> t = 256s + 64g + 16qd + c
__global__ __launch_bounds__(128, 2) void lti_kernel(
    const float*    __restrict__ x,       // [N, T] fp32 (skip-connection)
    const int*      __restrict__ cnt,     // [N]
    const unsigned* __restrict__ slots,   // [N, CAP]
    const float*    __restrict__ sscale,  // [N, CAP]
    float*          __restrict__ out)     // [N, T]
{
    const int n   = blockIdx.x;
    const int tid = threadIdx.x;
    const int pw  = tid >> 6;        // parity wave 0..1
    const int ln  = tid & 63;
    const int c   = ln & 15, g = ln >> 4;
    const int D   = 16 * c + 8 * g;

    __shared__ __align__(16) char  xs_all[2][3][RS];  // 2 waves x 3 bufs x 2080 B
    __shared__ __align__(16) char  kt_all[2][8][72];  // per-wave shifted taps table
    __shared__ __align__(16) float red[TT];           // parity-1 partials (8 KB)
    __shared__ unsigned bl[CAP];
    __shared__ float    bs[CAP];

    char (*xsb)[RS] = xs_all[pw];
    char (*kt)[72]  = kt_all[pw];

    {   // per-wave init: zero own taps table (pads persist across experts)
        if (ln < 36) ((int4*)&kt[0][0])[ln] = make_int4(0, 0, 0, 0);   // 576 B
    }
    if (tid < CAP) {
        bl[tid] = slots[(size_t)n * CAP + tid];
        bs[tid] = sscale[(size_t)n * CAP + tid];
    }
    int L = cnt[n]; if (L > CAP) L = CAP;
    __syncthreads();

    const int M = (L - pw + 1) >> 1;         // this wave's visit count
    #define IDX(I) (pw + 2 * (I))

    f32x4 acc[8];
    #pragma unroll
    for (int s = 0; s < 8; ++s) { acc[s][0]=0.f; acc[s][1]=0.f; acc[s][2]=0.f; acc[s][3]=0.f; }

    int   tw0, tw1, tw2;                     // tap dwords per stage
    float sc0, sc1, sc2;                     // combined scales per stage

    const int a_ = c & 7;
    const int s1 = ((a_ + 1) & 7) + 15 - c + 8 * g;   // b64-aligned by construction

    // Cluster: EXACTLY 4 VMEM ops (2 full DMAs + tail DMA + tap dword).
    #define ISSUE(S, P)                                                                \
    {                                                                                  \
        const unsigned sv = bl[P];                                                     \
        const int e0 = __builtin_amdgcn_readfirstlane((int)(sv & 16383u));             \
        const int s0 = __builtin_amdgcn_readfirstlane((int)(sv >> 14));                \
        const char* rb = g_xi8 + (size_t)s0 * RS;                                      \
        gload_lds16(rb + 16 * ln,        &xsb[S][0]);                                  \
        gload_lds16(rb + 16 * ln + 1024, &xsb[S][1024]);                               \
        if (ln < 2) gload_lds16(rb + 16 * ln + 2048, &xsb[S][2048]);                   \
        tw##S = *(const int*)(g_ki8 + ((size_t)e0 << 5) + 4 * (ln & 7));               \
        sc##S = bs[P];                                                                 \
    }

    #define COMMIT(S)                                                                  \
    {                                                                                  \
        const int a2 = ln >> 3, pad = (a2 + 1) & 7, mb = 4 * (ln & 7);                 \
        kt[a2][pad + 47 - mb] = (char)(tw##S);                                         \
        kt[a2][pad + 46 - mb] = (char)(tw##S >> 8);                                    \
        kt[a2][pad + 45 - mb] = (char)(tw##S >> 16);                                   \
        kt[a2][pad + 44 - mb] = (char)(tw##S >> 24);                                   \
    }

    #define COMPUTE(S)                                                                 \
    {                                                                                  \
        const long b1 = *(const long*)&kt[a_][s1];                                     \
        const long b2 = (g < 2) ? 0L : *(const long*)&kt[a_][s1 + 16];                 \
        const float scv = sc##S;                                                       \
        _Pragma("unroll")                                                              \
        for (int s = 0; s < 8; ++s) {                                                  \
            const long a1  = *(const long*)&xsb[S][256 * s + D];                       \
            const long a2v = *(const long*)&xsb[S][256 * s + D + 16];                  \
            int4v ti = {0, 0, 0, 0};                                                   \
            ti = __builtin_amdgcn_mfma_i32_16x16x32_i8(a1,  b1, ti, 0, 0, 0);          \
            ti = __builtin_amdgcn_mfma_i32_16x16x32_i8(a2v, b2, ti, 0, 0, 0);          \
            acc[s][0] += scv * (float)ti[0];                                           \
            acc[s][1] += scv * (float)ti[1];                                           \
            acc[s][2] += scv * (float)ti[2];                                           \
            acc[s][3] += scv * (float)ti[3];                                           \
        }                                                                              \
    }

    // BODY: issue visit I+2's cluster, wait for visit I's cluster, commit+compute.
    #define BODY(SC, SN, I)                                                            \
    if ((I) < M) {                                                                     \
        __builtin_amdgcn_sched_barrier(0);                                             \
        if ((I) + 2 < M) ISSUE(SN, IDX((I) + 2));                                      \
        const int rem = M - (I);                                                       \
        if (rem >= 3)      { asm volatile("s_waitcnt vmcnt(8)" ::: "memory"); }        \
        else if (rem == 2) { asm volatile("s_waitcnt vmcnt(4)" ::: "memory"); }        \
        else               { asm volatile("s_waitcnt vmcnt(0)" ::: "memory"); }        \
        __builtin_amdgcn_sched_barrier(0);                                             \
        COMMIT(SC);                                                                    \
        COMPUTE(SC);                                                                   \
    }

    if (M > 0) ISSUE(0, IDX(0));
    if (M > 1) ISSUE(1, IDX(1));
    for (int i = 0; i < M; i += 3) {
        BODY(0, 2, i);
        BODY(1, 0, i + 1);
        BODY(2, 1, i + 2);
    }

    // Parity combine (block-uniform control flow; acc==0 when M==0).
    if (pw == 1) {
        #pragma unroll
        for (int s = 0; s < 8; ++s)
            #pragma unroll
            for (int qd = 0; qd < 4; ++qd)
                red[256 * s + 64 * g + 16 * qd + c] = acc[s][qd];
    }
    __syncthreads();
    if (pw == 0) {
        const float* xr  = x   + (size_t)n * TT;
        float*       orw = out + (size_t)n * TT;
        #pragma unroll
        for (int s = 0; s < 8; ++s) {
            #pragma unroll
            for (int qd = 0; qd < 4; ++qd) {
                const int ta = 256 * s + 64 * g + 16 * qd + c;
                orw[ta] = xr[ta] + acc[s][qd] + red[ta];
            }
        }
    }
    #undef IDX
    #undef ISSUE
    #undef COMMIT
    #undef COMPUTE
    #undef BODY
}

extern "C" void kernel_launch(void* const* d_in, const int* in_sizes, int n_in,
                              void* d_out, int out_size, void* d_ws, size_t ws_size,
                              hipStream_t stream) {
    const float* x    = (const float*)d_in[0];
    const float* kern = (const float*)d_in[1];
    const int*   src  = (const int*)d_in[2];
    const int*   dst  = (const int*)d_in[3];
    float*       out  = (float*)d_out;

    int*      cnt    = (int*)d_ws;                            // 4 KB
    unsigned* slots  = (unsigned*)((char*)d_ws + 4096);       // 256 KB
    float*    sscale = (float*)((char*)d_ws + 4096 + 262144); // 256 KB

    cvt_kernel<<<dim3(NN + 1), dim3(256), 0, stream>>>(x, cnt);
    csr_kernel<<<dim3(EE / 256), dim3(256), 0, stream>>>(kern, src, dst, cnt, slots, sscale);
    lti_kernel<<<dim3(NN), dim3(128), 0, stream>>>(x, cnt, slots, sscale, out);
}

// Round 18
// 34.807 us; speedup vs baseline: 1.0059x; 1.0059x over previous
//
#include <hip/hip_runtime.h>
#include <hip/hip_bf16.h>

// Problem constants: B=1, N=1024, T=2048, E=16384, K=32.
#define TT  2048
#define KK  32
#define NN  1024
#define EE  16384
#define CAP 64     // per-row expert cap (Poisson(16); P(>64) ~ 1e-21)
#define RS  2080   // padded bf16 row stride: [32 causal zeros | 2048 row]

typedef short short8 __attribute__((ext_vector_type(8)));
typedef float f32x4  __attribute__((ext_vector_type(4)));

// Padded bf16 x rows (device global, rewritten every call).
__device__ short g_xbf[NN * RS];   // 4.26 MB

__device__ __forceinline__ short f2bf(float f) {
    __hip_bfloat16 h = __float2bfloat16(f);
    return __builtin_bit_cast(short, h);
}

// Async global->LDS DMA, 16 B per ACTIVE lane (dest = uniform base + lane*16).
__device__ __forceinline__ void gload_lds16(const short* g, short* l) {
    __builtin_amdgcn_global_load_lds(
        (const __attribute__((address_space(1))) void*)(const void*)(g),
        (__attribute__((address_space(3))) void*)(void*)(l), 16, 0, 0);
}

// Prep A: blocks 0..1023: x row -> padded bf16 row; block 1024: zero cnt.
__global__ __launch_bounds__(256) void cvt_kernel(const float* __restrict__ x,
                                                  int* __restrict__ cnt) {
    const int bid = blockIdx.x, tid = threadIdx.x;
    if (bid < NN) {
        const float4* xr = (const float4*)(x + (size_t)bid * TT);
        const float4 u = xr[2 * tid], v = xr[2 * tid + 1];
        short8 h;
        h[0]=f2bf(u.x); h[1]=f2bf(u.y); h[2]=f2bf(u.z); h[3]=f2bf(u.w);
        h[4]=f2bf(v.x); h[5]=f2bf(v.y); h[6]=f2bf(v.z); h[7]=f2bf(v.w);
        *(short8*)&g_xbf[(size_t)bid * RS + 32 + 8 * tid] = h;
        if (tid < 4) {
            short8 z; z[0]=0;z[1]=0;z[2]=0;z[3]=0;z[4]=0;z[5]=0;z[6]=0;z[7]=0;
            *(short8*)&g_xbf[(size_t)bid * RS + 8 * tid] = z;   // causal halo
        }
    } else {
        ((int4*)cnt)[tid] = make_int4(0, 0, 0, 0);              // 4 KB
    }
}

// Prep B: routing CSR. slots[d*CAP+p] packs (src<<14)|e.
__global__ __launch_bounds__(256) void csr_kernel(const int* __restrict__ src,
                                                  const int* __restrict__ dst,
                                                  int* __restrict__ cnt,
                                                  unsigned* __restrict__ slots) {
    const int e = blockIdx.x * 256 + threadIdx.x;   // 16384 threads
    const int d = dst[e];
    const int p = atomicAdd(&cnt[d], 1);
    if (p < CAP) slots[(size_t)d * CAP + p] = ((unsigned)src[e] << 14) | (unsigned)e;
}

// Main: grid 1024 (row n), 128 thr = 2 parity waves. ONE VISIT = ONE EXPERT OVER
// THE FULL ROW (16384 visits total). Per visit:
//   cluster = EXACTLY 6 VMEM {5x gload_lds (whole 4160B padded row, halo baked
//   in), 1x fp32 tap float4}; 3-deep rotation, counted vmcnt(12/6/0).
//   Then: kt commit (4 b16 writes), b1/b2 ds_reads ONCE (reused across the whole
//   row), 8 segments x {2 ds_read_b128 A-frags + 2 MFMA}.
// Verified MFMA math (R2-R16), full-row buffer xsb = padded row:
//   A1 b128 at xsb[256s + 16c + 8g], A2 at +16, s in [0,8)
//   b1 = kt[a][s1..+8), b2 = kt[a][s1+16..+24) with g<2 -> 0 (REQUIRED)
//   kt[a][((a+1)&7)+47-m] = tap[m];  a=c&7, s1=((a+1)&7)+15-c+8g (8-aligned)
//   D: col=c=lane&15, row=4g+qd -> t = 256s + 64g + 16qd + c
__global__ __launch_bounds__(128, 2) void lti_kernel(
    const float*    __restrict__ x,      // [N, T] fp32 (skip-connection + taps src)
    const float*    __restrict__ kern,   // [E, K] fp32
    const int*      __restrict__ cnt,    // [N]
    const unsigned* __restrict__ slots,  // [N, CAP]
    float*          __restrict__ out)    // [N, T]
{
    const int n   = blockIdx.x;
    const int tid = threadIdx.x;
    const int pw  = tid >> 6;        // parity wave 0..1
    const int ln  = tid & 63;
    const int c   = ln & 15, g = ln >> 4;
    const int D   = 16 * c + 8 * g;

    __shared__ __align__(16) short xs_all[2][3][RS];  // 2 waves x 3 bufs x 4160 B
    __shared__ __align__(16) short kt_all[2][8][72];  // per-wave shifted taps table
    __shared__ __align__(16) float red[TT];           // parity-1 partials (8 KB)
    __shared__ unsigned bl[CAP];

    short (*xsb)[RS] = xs_all[pw];
    short (*kt)[72]  = kt_all[pw];

    short8 z8; z8[0]=0;z8[1]=0;z8[2]=0;z8[3]=0;z8[4]=0;z8[5]=0;z8[6]=0;z8[7]=0;

    {   // per-wave init: zero own taps table (pads persist across experts)
        short8* kz = (short8*)&kt[0][0];   // 576 shorts = 72 short8
        kz[ln] = z8;
        if (ln < 8) kz[64 + ln] = z8;
    }
    if (tid < CAP) bl[tid] = slots[(size_t)n * CAP + tid];
    int L = cnt[n]; if (L > CAP) L = CAP;
    __syncthreads();

    const int M = (L - pw + 1) >> 1;         // this wave's visit count
    #define IDX(I) (pw + 2 * (I))

    f32x4 acc[8];
    #pragma unroll
    for (int s = 0; s < 8; ++s) { acc[s][0]=0.f; acc[s][1]=0.f; acc[s][2]=0.f; acc[s][3]=0.f; }

    float4 tr0, tr1, tr2;                    // tap regs per stage

    const int a_ = c & 7;
    const int s1 = ((a_ + 1) & 7) + 15 - c + 8 * g;   // b128-aligned by construction

    // Cluster: EXACTLY 6 VMEM ops (5 DMA staging the whole padded row + 1 tap).
    #define ISSUE(S, P)                                                                \
    {                                                                                  \
        const unsigned sv = bl[P];                                                     \
        const int e0 = __builtin_amdgcn_readfirstlane((int)(sv & 16383u));             \
        const int s0 = __builtin_amdgcn_readfirstlane((int)(sv >> 14));                \
        const short* rb = g_xbf + (size_t)s0 * RS;                                     \
        gload_lds16(rb + 8 * ln,        &xsb[S][0]);                                   \
        gload_lds16(rb + 8 * ln + 512,  &xsb[S][512]);                                 \
        gload_lds16(rb + 8 * ln + 1024, &xsb[S][1024]);                                \
        gload_lds16(rb + 8 * ln + 1536, &xsb[S][1536]);                                \
        if (ln < 4) gload_lds16(rb + 8 * ln + 2048, &xsb[S][2048]);                    \
        tr##S = *(const float4*)(kern + ((size_t)e0 << 5) + 4 * (ln & 7));             \
    }

    #define COMMIT(S)                                                                  \
    {                                                                                  \
        const int a2 = ln >> 3, pad = (a2 + 1) & 7, mb = 4 * (ln & 7);                 \
        kt[a2][pad + 47 - mb] = f2bf(tr##S.x);                                         \
        kt[a2][pad + 46 - mb] = f2bf(tr##S.y);                                         \
        kt[a2][pad + 45 - mb] = f2bf(tr##S.z);                                         \
        kt[a2][pad + 44 - mb] = f2bf(tr##S.w);                                         \
    }

    #define COMPUTE(S)                                                                 \
    {                                                                                  \
        const short8 b1 = *(const short8*)&kt[a_][s1];                                 \
        short8 b2 = *(const short8*)&kt[a_][s1 + 16];                                  \
        if (g < 2) b2 = z8;   /* k<16 zeroing is REQUIRED */                           \
        _Pragma("unroll")                                                              \
        for (int s = 0; s < 8; ++s) {                                                  \
            const short8 a1  = *(const short8*)&xsb[S][256 * s + D];                   \
            const short8 a2v = *(const short8*)&xsb[S][256 * s + D + 16];              \
            acc[s] = __builtin_amdgcn_mfma_f32_16x16x32_bf16(a1,  b1, acc[s], 0,0,0);  \
            acc[s] = __builtin_amdgcn_mfma_f32_16x16x32_bf16(a2v, b2, acc[s], 0,0,0);  \
        }                                                                              \
    }

    // BODY: issue visit I+2's cluster, wait for visit I's cluster, commit+compute.
    #define BODY(SC, SN, I)                                                            \
    if ((I) < M) {                                                                     \
        __builtin_amdgcn_sched_barrier(0);                                             \
        if ((I) + 2 < M) ISSUE(SN, IDX((I) + 2));                                      \
        const int rem = M - (I);                                                       \
        if (rem >= 3)      { asm volatile("s_waitcnt vmcnt(12)" ::: "memory"); }       \
        else if (rem == 2) { asm volatile("s_waitcnt vmcnt(6)"  ::: "memory"); }       \
        else               { asm volatile("s_waitcnt vmcnt(0)"  ::: "memory"); }       \
        __builtin_amdgcn_sched_barrier(0);                                             \
        COMMIT(SC);                                                                    \
        COMPUTE(SC);                                                                   \
    }

    if (M > 0) ISSUE(0, IDX(0));
    if (M > 1) ISSUE(1, IDX(1));
    for (int i = 0; i < M; i += 3) {
        BODY(0, 2, i);
        BODY(1, 0, i + 1);
        BODY(2, 1, i + 2);
    }

    // Parity combine (block-uniform control flow; acc==0 when M==0).
    if (pw == 1) {
        #pragma unroll
        for (int s = 0; s < 8; ++s)
            #pragma unroll
            for (int qd = 0; qd < 4; ++qd)
                red[256 * s + 64 * g + 16 * qd + c] = acc[s][qd];
    }
    __syncthreads();
    if (pw == 0) {
        const float* xr  = x   + (size_t)n * TT;
        float*       orw = out + (size_t)n * TT;
        #pragma unroll
        for (int s = 0; s < 8; ++s) {
            #pragma unroll
            for (int qd = 0; qd < 4; ++qd) {
                const int ta = 256 * s + 64 * g + 16 * qd + c;
                orw[ta] = xr[ta] + acc[s][qd] + red[ta];
            }
        }
    }
    #undef IDX
    #undef ISSUE
    #undef COMMIT
    #undef COMPUTE
    #undef BODY
}

extern "C" void kernel_launch(void* const* d_in, const int* in_sizes, int n_in,
                              void* d_out, int out_size, void* d_ws, size_t ws_size,
                              hipStream_t stream) {
    const float* x    = (const float*)d_in[0];
    const float* kern = (const float*)d_in[1];
    const int*   src  = (const int*)d_in[2];
    const int*   dst  = (const int*)d_in[3];
    float*       out  = (float*)d_out;

    int*      cnt   = (int*)d_ws;                       // 4 KB
    unsigned* slots = (unsigned*)((char*)d_ws + 4096);  // 256 KB

    cvt_kernel<<<dim3(NN + 1), dim3(256), 0, stream>>>(x, cnt);
    csr_kernel<<<dim3(EE / 256), dim3(256), 0, stream>>>(src, dst, cnt, slots);
    lti_kernel<<<dim3(NN), dim3(128), 0, stream>>>(x, kern, cnt, slots, out);
}